// Round 3
// baseline (240.852 us; speedup 1.0000x reference)
//
#include <hip/hip_runtime.h>
#include <math.h>

// ---------------- LDS layout (floats), per 128-thread (2-wave) block --------
// Layer-1 is barrier-free: each wave owns a private zone Z_w holding, in
// time-sequence (wave-ordered DS makes overlays safe):
//   T2 [32 prefixes][36]          (step2 write -> step3 read)    1152
//   T3 [16 rows][34] (overlay)    (step3 write -> step4 read)     544
//   EX [64 lanes][18] (overlay)   (partial exchange, post-loop)  1152
#define WC3   0      // l1c3 [q3][m4][n4][q4]                      128
#define WC2   128    // l1c2 [q2][m3][n3][q3]                      128
#define WU1   256    // l2c1                                        32  -> 288
#define Z0    288    // wave0 zone (1152)                               -> 1440
#define Z1    1440   // wave1 zone (1152)                               -> 2592
#define H1O   288    // h1 (2048) overlays Z0/Z1 after exchange         -> 2336
#define BO    2336   // B[128][9] = 1152                                -> 3488
#define CO    3488   // C[32][17] = 544                                 -> 4032
#define DO    4032   // D[16][17] = 272                                 -> 4304
#define H2O   4304   // 64                                              -> 4368
#define H3O   4368   // 32                                              -> 4400
#define LDS_FLOATS 4400   // 17600 B -> 8 blocks/CU resident = 16 waves/CU

// Setup: dense layer-3 matrix W3[mi(32)][nj(64)] from TT cores (tiny).
__global__ void tt_setup_w3(const float* __restrict__ v0, const float* __restrict__ v1,
                            const float* __restrict__ v2, const float* __restrict__ v3,
                            const float* __restrict__ v4, float* __restrict__ w3) {
    int i = blockIdx.x * 256 + threadIdx.x;
    if (i >= 2048) return;
    int mi = i >> 6, nj = i & 63;
    int m1 = (mi >> 4) & 1, m2 = (mi >> 3) & 1, m3 = (mi >> 2) & 1, m4 = (mi >> 1) & 1, m5 = mi & 1;
    int n1 = (nj >> 4) & 3, n2 = (nj >> 3) & 1, n3 = (nj >> 2) & 1, n4 = (nj >> 1) & 1, n5 = nj & 1;
    float s = 0.f;
#pragma unroll
    for (int q1 = 0; q1 < 2; ++q1) {
        float a1 = v0[(m1 * 4 + n1) * 2 + q1];
#pragma unroll
        for (int q2 = 0; q2 < 2; ++q2) {
            float a2 = a1 * v1[((q1 * 2 + m2) * 2 + n2) * 2 + q2];
#pragma unroll
            for (int q3 = 0; q3 < 2; ++q3) {
                float a3 = a2 * v2[((q2 * 2 + m3) * 2 + n3) * 2 + q3];
#pragma unroll
                for (int q4 = 0; q4 < 2; ++q4)
                    s = fmaf(a3 * v3[((q3 * 2 + m4) * 2 + n4) * 2 + q4],
                             v4[(q4 * 2 + m5) * 2 + n5], s);
            }
        }
    }
    w3[i] = s;
}

__global__ __launch_bounds__(128)
__attribute__((amdgpu_waves_per_eu(3)))
void tt_main(const float* __restrict__ x,
             const float* __restrict__ g0, const float* __restrict__ g1,
             const float* __restrict__ g2, const float* __restrict__ g3,
             const float* __restrict__ g4, const float* __restrict__ b1g,
             const float* __restrict__ u0, const float* __restrict__ u1,
             const float* __restrict__ u2, const float* __restrict__ u3,
             const float* __restrict__ u4, const float* __restrict__ b2g,
             const float* __restrict__ b3g,
             const float* __restrict__ Wmg, const float* __restrict__ blg,
             const float* __restrict__ w3g,
             float* __restrict__ out)
{
    __shared__ float smem[LDS_FLOATS];
    const int t   = threadIdx.x;
    const int tl  = t & 63;        // lane within wave
    const int wid = t >> 6;        // wave id = n2-half owned by this wave
    const int b = blockIdx.x;
    const float* xb = x + (size_t)b * 12288;

    // ---- issue x loads for this wave's first slab (slice s = wid) ----
    float xv[32];
    {
        const float4* xq = (const float4*)xb + wid * 512 + tl * 8;
#pragma unroll
        for (int i = 0; i < 8; ++i) {
            const float4 v = xq[i];
            xv[i*4+0] = v.x; xv[i*4+1] = v.y; xv[i*4+2] = v.z; xv[i*4+3] = v.w;
        }
    }

    // ---- non-uniformly-indexed weights to LDS (128 threads: one shot each) ----
    smem[WC3 + t] = g3[t];
    smem[WC2 + t] = g2[t];
    if (t < 32) smem[WU1 + t] = u1[t];
    __syncthreads();  // weights ready (the ONLY pre-exchange barrier)

    const int h = tl & 1;       // n4-half owned by this lane
    const int p = tl >> 1;      // subslice-local prefix (n2l*8 + n3)
    const int ZW = wid ? Z1 : Z0;   // wave-private zone

    float regT4[36];            // [jj(4)][n1(3)*3+q1(3)], partial over own n2-half
#pragma unroll
    for (int i = 0; i < 36; ++i) regT4[i] = 0.f;

#pragma unroll
    for (int n1 = 0; n1 < 3; ++n1) {
        // ---- step 1: t1[n4l*8 + m5*2+q4] = sum_n5 x * C4  (C4 uniform: s_load)
        float t1[32];
#pragma unroll
        for (int m5 = 0; m5 < 4; ++m5)
#pragma unroll
        for (int q4 = 0; q4 < 2; ++q4) {
            const float* w = g4 + (q4 * 4 + m5) * 8;
#pragma unroll
            for (int n4l = 0; n4l < 4; ++n4l) {
                float sa = xv[n4l*8+0] * w[0];
#pragma unroll
                for (int n5 = 1; n5 < 8; ++n5) sa = fmaf(xv[n4l*8+n5], w[n5], sa);
                t1[n4l*8 + m5*2 + q4] = sa;
            }
        }

        // xv is dead now: prefetch next slab (slice (n1+1)*2 + wid) INTO xv.
        if (n1 < 2) {
            const float4* xq = (const float4*)xb + ((n1 + 1) * 2 + wid) * 512 + tl * 8;
#pragma unroll
            for (int i = 0; i < 8; ++i) {
                const float4 v = xq[i];
                xv[i*4+0] = v.x; xv[i*4+1] = v.y; xv[i*4+2] = v.z; xv[i*4+3] = v.w;
            }
        }

        // ---- step 2: acc[m4*4+m5] (q3 = h), contract n4 (own half + partner
        //      half via shfl_xor) and q4
        float acc[16];
#pragma unroll
        for (int i = 0; i < 16; ++i) acc[i] = 0.f;
#pragma unroll
        for (int pass = 0; pass < 2; ++pass) {
            const int hh = (pass == 0) ? h : (1 - h);
            if (pass == 1) {
#pragma unroll
                for (int i = 0; i < 32; ++i) t1[i] = __shfl_xor(t1[i], 1);
            }
#pragma unroll
            for (int m4 = 0; m4 < 4; ++m4) {
                const int cbase = WC3 + ((h * 4 + m4) * 8 + hh * 4) * 2;  // q3 = h
                const float4 c0 = *(const float4*)&smem[cbase];
                const float4 c1 = *(const float4*)&smem[cbase + 4];
                const float cs[8] = {c0.x, c0.y, c0.z, c0.w, c1.x, c1.y, c1.z, c1.w};
#pragma unroll
                for (int m5 = 0; m5 < 4; ++m5) {
                    float sa = acc[m4*4+m5];
#pragma unroll
                    for (int n4l = 0; n4l < 4; ++n4l)
#pragma unroll
                    for (int q4 = 0; q4 < 2; ++q4)
                        sa = fmaf(t1[n4l*8 + m5*2 + q4], cs[n4l*2 + q4], sa);
                    acc[m4*4+m5] = sa;
                }
            }
        }

        // T2 write (wave-private zone; wave-ordered DS, compiler fence only)
        asm volatile("" ::: "memory");
#pragma unroll
        for (int m45 = 0; m45 < 16; ++m45)
            smem[ZW + p * 36 + m45 * 2 + h] = acc[m45];
        asm volatile("" ::: "memory");

        // ---- step 3: contract n3 (half per lane) & q3 -> T3 rows (LOCAL 0..15)
        {
            const int n3h = tl & 1;
            const int q2  = (tl >> 1) & 1;
            const int m3  = (tl >> 2) & 3;
            const int n2l = tl >> 4;
            float o3[16];
#pragma unroll
            for (int i = 0; i < 16; ++i) o3[i] = 0.f;
#pragma unroll
            for (int n3l = 0; n3l < 4; ++n3l) {
                const int rb = ZW + (n2l * 8 + n3h * 4 + n3l) * 36;
                float rv[32];
#pragma unroll
                for (int g = 0; g < 8; ++g) {
                    const float4 v = *(const float4*)&smem[rb + g * 4];
                    rv[g*4+0] = v.x; rv[g*4+1] = v.y; rv[g*4+2] = v.z; rv[g*4+3] = v.w;
                }
                const int wb = WC2 + ((q2 * 4 + m3) * 8 + n3h * 4 + n3l) * 2;
                const float w0 = smem[wb], w1 = smem[wb + 1];
#pragma unroll
                for (int m45 = 0; m45 < 16; ++m45)
                    o3[m45] = fmaf(rv[m45*2], w0, fmaf(rv[m45*2+1], w1, o3[m45]));
            }
#pragma unroll
            for (int k = 0; k < 16; ++k) o3[k] += __shfl_xor(o3[k], 1);
            asm volatile("" ::: "memory");   // all T2 reads precede T3 overlay writes
            const int row = n2l * 4 + m3;    // local row (own n2-half)
#pragma unroll
            for (int k = 0; k < 8; ++k) {
                const float v = n3h ? o3[8 + k] : o3[k];
                smem[ZW + row * 34 + (n3h * 8 + k) * 2 + q2] = v;
            }
            asm volatile("" ::: "memory");
        }

        // ---- step 4: contract own n2-half (4 rows) & q2 -> regT4, ALL 4 jj
        {
            const int m3 = tl >> 4, m4 = (tl >> 2) & 3, m5 = tl & 3;
            float2 zz[4];
#pragma unroll
            for (int l = 0; l < 4; ++l)
                zz[l] = *(const float2*)&smem[ZW + (l * 4 + m3) * 34 + (m4 * 4 + m5) * 2];
#pragma unroll
            for (int jj = 0; jj < 4; ++jj)
#pragma unroll
            for (int q1 = 0; q1 < 3; ++q1) {
                float sa = regT4[jj * 9 + n1 * 3 + q1];
#pragma unroll
                for (int g = 0; g < 2; ++g) {   // local n2 pairs; global n2 = wid*4 + g*2 {+1}
                    const float4 w = *(const float4*)(g1 + ((q1 * 4 + jj) * 8 + wid * 4 + g * 2) * 2);
                    sa = fmaf(zz[g*2].x,   w.x, sa);
                    sa = fmaf(zz[g*2].y,   w.y, sa);
                    sa = fmaf(zz[g*2+1].x, w.z, sa);
                    sa = fmaf(zz[g*2+1].y, w.w, sa);
                }
                regT4[jj * 9 + n1 * 3 + q1] = sa;
            }
        }
        asm volatile("" ::: "memory");
    } // n1  (NO barriers in this loop)

    // ---- hoist bias loads: in flight across the exchange barriers ----
    float bia[2][8];
#pragma unroll
    for (int j = 0; j < 2; ++j) {
        const int jj = wid * 2 + j;
#pragma unroll
        for (int m1 = 0; m1 < 8; ++m1) bia[j][m1] = b1g[m1 * 256 + jj * 64 + tl];
    }

    // ---- partial exchange: wave w ships partials for the PARTNER's jj pair ----
    {
        const int pbase = (1 - wid) * 18;   // partner pair {2(1-w), 2(1-w)+1}
        asm volatile("" ::: "memory");
#pragma unroll
        for (int kk = 0; kk < 9; ++kk) {
            float2 v; v.x = regT4[pbase + 2*kk]; v.y = regT4[pbase + 2*kk + 1];
            *(float2*)&smem[ZW + tl * 18 + 2 * kk] = v;
        }
    }
    __syncthreads();   // EX published
    {
        const int ZP = wid ? Z0 : Z1;       // partner zone holds OUR pair's partials
        const int obase = wid * 18;         // own pair {2w, 2w+1}
#pragma unroll
        for (int kk = 0; kk < 9; ++kk) {
            const float2 v = *(const float2*)&smem[ZP + tl * 18 + 2 * kk];
            regT4[obase + 2*kk]     += v.x;
            regT4[obase + 2*kk + 1] += v.y;
        }
    }
    __syncthreads();   // EX consumed; h1 may overlay Z0/Z1

    // ---- step 5: contract n1,q1 + bias + relu -> h1 (this wave's jj pair)
#pragma unroll
    for (int j = 0; j < 2; ++j) {
        const int jj = wid * 2 + j;
        const int rb = (wid * 2 + j) * 9;
#pragma unroll
        for (int m1 = 0; m1 < 8; ++m1) {
            float sa = bia[j][m1];
#pragma unroll
            for (int n1 = 0; n1 < 3; ++n1)
#pragma unroll
            for (int q1 = 0; q1 < 3; ++q1)
                sa = fmaf(regT4[rb + n1 * 3 + q1], g0[(m1 * 3 + n1) * 3 + q1], sa);
            smem[H1O + m1 * 256 + jj * 64 + tl] = fmaxf(sa, 0.f);
        }
    }
    __syncthreads();

    // ================= layer 2 (right-to-left) =================
    // L2a: contract n5(4) -> A[P][m5*2+q4], IN PLACE over h1 (elementwise per P)
#pragma unroll
    for (int pp = 0; pp < 4; ++pp) {
        const int P = pp * 128 + t;
        float4* ap = (float4*)&smem[H1O + P * 4];
        const float4 hv = *ap;
        float4 av;
        av.x = hv.x*u4[0]  + hv.y*u4[1]  + hv.z*u4[2]  + hv.w*u4[3];   // m5=0,q4=0
        av.y = hv.x*u4[8]  + hv.y*u4[9]  + hv.z*u4[10] + hv.w*u4[11];  // m5=0,q4=1
        av.z = hv.x*u4[4]  + hv.y*u4[5]  + hv.z*u4[6]  + hv.w*u4[7];   // m5=1,q4=0
        av.w = hv.x*u4[12] + hv.y*u4[13] + hv.z*u4[14] + hv.w*u4[15];  // m5=1,q4=1
        *ap = av;
    }
    __syncthreads();

    // L2b: contract n4(4),q4 -> B[p3][(m4*2+m5)*2+q3]  (p3 = t, one shot)
    {
        float4 aa[4];
#pragma unroll
        for (int n4 = 0; n4 < 4; ++n4)
            aa[n4] = *(const float4*)&smem[H1O + (t * 4 + n4) * 4];
        float o[8];
#pragma unroll
        for (int i = 0; i < 8; ++i) o[i] = 0.f;
#pragma unroll
        for (int n4 = 0; n4 < 4; ++n4)
#pragma unroll
        for (int q4 = 0; q4 < 2; ++q4) {
            const float a0 = q4 ? aa[n4].y : aa[n4].x;   // m5=0
            const float a1 = q4 ? aa[n4].w : aa[n4].z;   // m5=1
#pragma unroll
            for (int q3 = 0; q3 < 2; ++q3)
#pragma unroll
            for (int m4 = 0; m4 < 2; ++m4) {
                const float w = u3[((q3 * 2 + m4) * 4 + n4) * 2 + q4];
                o[(m4 * 2 + 0) * 2 + q3] = fmaf(a0, w, o[(m4 * 2 + 0) * 2 + q3]);
                o[(m4 * 2 + 1) * 2 + q3] = fmaf(a1, w, o[(m4 * 2 + 1) * 2 + q3]);
            }
        }
#pragma unroll
        for (int k = 0; k < 8; ++k) smem[BO + t * 9 + k] = o[k];
    }
    __syncthreads();

    // L2c: contract n3(4),q3 -> C[p2][(m3*4+m45)*2+q2]  (U2 uniform)
    if (t < 32) {
        float o[16];
#pragma unroll
        for (int i = 0; i < 16; ++i) o[i] = 0.f;
#pragma unroll
        for (int n3 = 0; n3 < 4; ++n3)
#pragma unroll
        for (int q3 = 0; q3 < 2; ++q3) {
            float zb[4];
#pragma unroll
            for (int m45 = 0; m45 < 4; ++m45)
                zb[m45] = smem[BO + (t * 4 + n3) * 9 + m45 * 2 + q3];
#pragma unroll
            for (int m3 = 0; m3 < 2; ++m3)
#pragma unroll
            for (int q2 = 0; q2 < 2; ++q2) {
                const float w = u2[((q2 * 2 + m3) * 4 + n3) * 2 + q3];
#pragma unroll
                for (int m45 = 0; m45 < 4; ++m45)
                    o[(m3 * 4 + m45) * 2 + q2] = fmaf(zb[m45], w, o[(m3 * 4 + m45) * 2 + q2]);
            }
        }
#pragma unroll
        for (int k = 0; k < 16; ++k) smem[CO + t * 17 + k] = o[k];
    }
    __syncthreads();

    // L2d: contract n2(4),q2 -> D[s][n1*2+q1]  (U1 non-uniform: LDS)
    if (t < 32) {
        const int n1 = t >> 2, m2 = (t >> 1) & 1, m3 = t & 1;
        float o[8];
#pragma unroll
        for (int i = 0; i < 8; ++i) o[i] = 0.f;
#pragma unroll
        for (int n2 = 0; n2 < 4; ++n2)
#pragma unroll
        for (int q2 = 0; q2 < 2; ++q2) {
            float cb[4];
#pragma unroll
            for (int m45 = 0; m45 < 4; ++m45)
                cb[m45] = smem[CO + (n1 * 4 + n2) * 17 + (m3 * 4 + m45) * 2 + q2];
#pragma unroll
            for (int q1 = 0; q1 < 2; ++q1) {
                const float w = smem[WU1 + ((q1 * 2 + m2) * 4 + n2) * 2 + q2];
#pragma unroll
                for (int m45 = 0; m45 < 4; ++m45)
                    o[m45 * 2 + q1] = fmaf(cb[m45], w, o[m45 * 2 + q1]);
            }
        }
#pragma unroll
        for (int m45 = 0; m45 < 4; ++m45)
#pragma unroll
        for (int q1 = 0; q1 < 2; ++q1)
            smem[DO + (m2 * 8 + m3 * 4 + m45) * 17 + n1 * 2 + q1] = o[m45 * 2 + q1];
    }
    __syncthreads();

    // L2e: contract n1(8),q1 + bias + relu -> h2  (U0 uniform)
    if (t < 16) {
        float o[4];
#pragma unroll
        for (int i = 0; i < 4; ++i) o[i] = 0.f;
#pragma unroll
        for (int n1 = 0; n1 < 8; ++n1)
#pragma unroll
        for (int q1 = 0; q1 < 2; ++q1) {
            const float dv = smem[DO + t * 17 + n1 * 2 + q1];
#pragma unroll
            for (int m1 = 0; m1 < 4; ++m1)
                o[m1] = fmaf(dv, u0[(m1 * 8 + n1) * 2 + q1], o[m1]);
        }
#pragma unroll
        for (int m1 = 0; m1 < 4; ++m1)
            smem[H2O + m1 * 16 + t] = fmaxf(o[m1] + b2g[m1 * 16 + t], 0.f);
    }
    __syncthreads();

    // ---- layer 3 dense (W3 32x64 from d_ws) + relu ----
    if (t < 32) {
        const float4* wr = (const float4*)(w3g + t * 64);
        float sa = b3g[t];
#pragma unroll
        for (int g = 0; g < 16; ++g) {
            const float4 w4 = wr[g];
            sa = fmaf(w4.x, smem[H2O + g*4 + 0],
                 fmaf(w4.y, smem[H2O + g*4 + 1],
                 fmaf(w4.z, smem[H2O + g*4 + 2],
                 fmaf(w4.w, smem[H2O + g*4 + 3], sa))));
        }
        smem[H3O + t] = fmaxf(sa, 0.f);
    }
    __syncthreads();

    // ---- head: logits + log_softmax (wave 0 only) ----
    if (t < 64) {
        const int k = t & 31;
        float pr = smem[H3O + k] * Wmg[t];   // t = c*32 + k
#pragma unroll
        for (int d = 16; d >= 1; d >>= 1) pr += __shfl_xor(pr, d);
        const float l0 = __shfl(pr, 0) + blg[0];
        const float l1 = __shfl(pr, 32) + blg[1];
        if (t == 0) {
            const float mm = fmaxf(l0, l1);
            const float lse = mm + logf(expf(l0 - mm) + expf(l1 - mm));
            out[(size_t)b * 2 + 0] = l0 - lse;
            out[(size_t)b * 2 + 1] = l1 - lse;
        }
    }
}

extern "C" void kernel_launch(void* const* d_in, const int* in_sizes, int n_in,
                              void* d_out, int out_size, void* d_ws, size_t ws_size,
                              hipStream_t stream) {
    const float* x    = (const float*)d_in[0];
    const float* l1c0 = (const float*)d_in[1];
    const float* l1c1 = (const float*)d_in[2];
    const float* l1c2 = (const float*)d_in[3];
    const float* l1c3 = (const float*)d_in[4];
    const float* l1c4 = (const float*)d_in[5];
    const float* b1   = (const float*)d_in[6];
    const float* l2c0 = (const float*)d_in[7];
    const float* l2c1 = (const float*)d_in[8];
    const float* l2c2 = (const float*)d_in[9];
    const float* l2c3 = (const float*)d_in[10];
    const float* l2c4 = (const float*)d_in[11];
    const float* b2   = (const float*)d_in[12];
    const float* l3c0 = (const float*)d_in[13];
    const float* l3c1 = (const float*)d_in[14];
    const float* l3c2 = (const float*)d_in[15];
    const float* l3c3 = (const float*)d_in[16];
    const float* l3c4 = (const float*)d_in[17];
    const float* b3   = (const float*)d_in[18];
    const float* Wm   = (const float*)d_in[19];
    const float* bl   = (const float*)d_in[20];
    float* W3 = (float*)d_ws;  // 2048 floats scratch

    tt_setup_w3<<<8, 256, 0, stream>>>(l3c0, l3c1, l3c2, l3c3, l3c4, W3);
    tt_main<<<2048, 128, 0, stream>>>(x, l1c0, l1c1, l1c2, l1c3, l1c4, b1,
                                      l2c0, l2c1, l2c2, l2c3, l2c4, b2, b3,
                                      Wm, bl, W3, (float*)d_out);
}

// Round 4
// 222.764 us; speedup vs baseline: 1.0812x; 1.0812x over previous
//
#include <hip/hip_runtime.h>
#include <math.h>

// ---------------- LDS layout (floats), per 64-thread (1-wave) block ----------
// Single wave => in-order DS ops make same-wave LDS RAW/WAR safe with no
// barriers; T2/T3 are double-buffered so adjacent slices touch disjoint
// buffers and the compiler may overlap iterations (cross-slice ILP).
#define WC3  0      // l1c3 [q3][m4][n4][q4]            128
#define WC2  128    // l1c2 [q2][m3][n3][q3]            128
#define WU1  256    // l2c1                              32  -> 288
#define T2A  288    // T2 [32][36], slices s even       1152 -> 1440
#define T2B  1440   // T2 [32][36], slices s odd        1152 -> 2592
#define T3A  2592   // T3 [32][34], n1 even             1088 -> 3680
#define T3B  3680   // T3 [32][34], n1 odd              1088 -> 4768
#define H1O  288    // h1 (2048) overlays T2A/T2B after the loop  -> 2336
#define BO   2336   // B[128][9] = 1152 (over dead T3A; written after its reads)
#define CO   288    // C[32][17] = 544  (over dead h1 head)       -> 832
#define DO   832    // D[16][17] = 272                            -> 1104
#define H2O  1104   // 64                                         -> 1168
#define H3O  1168   // 32                                         -> 1200
#define LDS_FLOATS 4768   // 19072 B -> 8 blocks/CU (= grid cap of 8 waves/CU)

// Setup: dense layer-3 matrix W3[mi(32)][nj(64)] from TT cores (tiny).
__global__ void tt_setup_w3(const float* __restrict__ v0, const float* __restrict__ v1,
                            const float* __restrict__ v2, const float* __restrict__ v3,
                            const float* __restrict__ v4, float* __restrict__ w3) {
    int i = blockIdx.x * 256 + threadIdx.x;
    if (i >= 2048) return;
    int mi = i >> 6, nj = i & 63;
    int m1 = (mi >> 4) & 1, m2 = (mi >> 3) & 1, m3 = (mi >> 2) & 1, m4 = (mi >> 1) & 1, m5 = mi & 1;
    int n1 = (nj >> 4) & 3, n2 = (nj >> 3) & 1, n3 = (nj >> 2) & 1, n4 = (nj >> 1) & 1, n5 = nj & 1;
    float s = 0.f;
#pragma unroll
    for (int q1 = 0; q1 < 2; ++q1) {
        float a1 = v0[(m1 * 4 + n1) * 2 + q1];
#pragma unroll
        for (int q2 = 0; q2 < 2; ++q2) {
            float a2 = a1 * v1[((q1 * 2 + m2) * 2 + n2) * 2 + q2];
#pragma unroll
            for (int q3 = 0; q3 < 2; ++q3) {
                float a3 = a2 * v2[((q2 * 2 + m3) * 2 + n3) * 2 + q3];
#pragma unroll
                for (int q4 = 0; q4 < 2; ++q4)
                    s = fmaf(a3 * v3[((q3 * 2 + m4) * 2 + n4) * 2 + q4],
                             v4[(q4 * 2 + m5) * 2 + n5], s);
            }
        }
    }
    w3[i] = s;
}

__global__ __launch_bounds__(64, 2)
void tt_main(const float* __restrict__ x,
             const float* __restrict__ g0, const float* __restrict__ g1,
             const float* __restrict__ g2, const float* __restrict__ g3,
             const float* __restrict__ g4, const float* __restrict__ b1g,
             const float* __restrict__ u0, const float* __restrict__ u1,
             const float* __restrict__ u2, const float* __restrict__ u3,
             const float* __restrict__ u4, const float* __restrict__ b2g,
             const float* __restrict__ b3g,
             const float* __restrict__ Wmg, const float* __restrict__ blg,
             const float* __restrict__ w3g,
             float* __restrict__ out)
{
    __shared__ float smem[LDS_FLOATS];
    const int t = threadIdx.x;
    const int b = blockIdx.x;
    const float* xb = x + (size_t)b * 12288;

    // ---- issue x loads for subslice 0 (lane t owns 32 contiguous floats) ----
    float xv[32];
    {
        const float4* xq = (const float4*)xb + t * 8;
#pragma unroll
        for (int i = 0; i < 8; ++i) {
            const float4 v = xq[i];
            xv[i*4+0] = v.x; xv[i*4+1] = v.y; xv[i*4+2] = v.z; xv[i*4+3] = v.w;
        }
    }

    // ---- non-uniformly-indexed weights to LDS ----
    smem[WC3 + t] = g3[t];  smem[WC3 + 64 + t] = g3[64 + t];
    smem[WC2 + t] = g2[t];  smem[WC2 + 64 + t] = g2[64 + t];
    if (t < 32) smem[WU1 + t] = u1[t];
    __syncthreads();  // weights ready (1-wave: lowers to a waitcnt)

    const int h = t & 1;       // n4-half owned by this lane
    const int p = t >> 1;      // subslice-local prefix (n2l*8 + n3)

    float regT4[36];           // [jj(4)][n1(3)*3+q1(3)] accumulated across slices
#pragma unroll
    for (int i = 0; i < 36; ++i) regT4[i] = 0.f;

#pragma unroll
    for (int n1 = 0; n1 < 3; ++n1) {
        const int T3S = (n1 & 1) ? T3B : T3A;
#pragma unroll
        for (int n2h = 0; n2h < 2; ++n2h) {
            const int s = n1 * 2 + n2h;
            const int T2S = (s & 1) ? T2B : T2A;

            // ---- step 1: t1[n4l*8 + m5*2+q4] = sum_n5 x * C4  (C4 uniform)
            float t1[32];
#pragma unroll
            for (int m5 = 0; m5 < 4; ++m5)
#pragma unroll
            for (int q4 = 0; q4 < 2; ++q4) {
                const float* w = g4 + (q4 * 4 + m5) * 8;
#pragma unroll
                for (int n4l = 0; n4l < 4; ++n4l) {
                    float sa = xv[n4l*8+0] * w[0];
#pragma unroll
                    for (int n5 = 1; n5 < 8; ++n5) sa = fmaf(xv[n4l*8+n5], w[n5], sa);
                    t1[n4l*8 + m5*2 + q4] = sa;
                }
            }

            // xv is dead: prefetch next slab INTO xv (zero extra registers;
            // latency hides under steps 2-4 of this slice).
            if (s < 5) {
                const float4* xq = (const float4*)xb + (s + 1) * 512 + t * 8;
#pragma unroll
                for (int i = 0; i < 8; ++i) {
                    const float4 v = xq[i];
                    xv[i*4+0] = v.x; xv[i*4+1] = v.y; xv[i*4+2] = v.z; xv[i*4+3] = v.w;
                }
            }

            // ---- step 2: acc[m4*4+m5] (q3 = h), contract n4 (own half, then
            //      partner's half via shfl_xor) and q4
            float acc[16];
#pragma unroll
            for (int i = 0; i < 16; ++i) acc[i] = 0.f;
#pragma unroll
            for (int pass = 0; pass < 2; ++pass) {
                const int hh = (pass == 0) ? h : (1 - h);
                if (pass == 1) {
#pragma unroll
                    for (int i = 0; i < 32; ++i) t1[i] = __shfl_xor(t1[i], 1);
                }
#pragma unroll
                for (int m4 = 0; m4 < 4; ++m4) {
                    const int cbase = WC3 + ((h * 4 + m4) * 8 + hh * 4) * 2;  // q3 = h
                    const float4 c0 = *(const float4*)&smem[cbase];
                    const float4 c1 = *(const float4*)&smem[cbase + 4];
                    const float cs[8] = {c0.x, c0.y, c0.z, c0.w, c1.x, c1.y, c1.z, c1.w};
#pragma unroll
                    for (int m5 = 0; m5 < 4; ++m5) {
                        float sa = acc[m4*4+m5];
#pragma unroll
                        for (int n4l = 0; n4l < 4; ++n4l)
#pragma unroll
                        for (int q4 = 0; q4 < 2; ++q4)
                            sa = fmaf(t1[n4l*8 + m5*2 + q4], cs[n4l*2 + q4], sa);
                        acc[m4*4+m5] = sa;
                    }
                }
            }

            // T2 write (double-buffered; single wave => no fence needed)
#pragma unroll
            for (int m45 = 0; m45 < 16; ++m45)
                smem[T2S + p * 36 + m45 * 2 + h] = acc[m45];

            // ---- step 3: contract n3 (half per lane) & q3 -> T3 rows
            {
                const int n3h = t & 1;
                const int q2  = (t >> 1) & 1;
                const int m3  = (t >> 2) & 3;
                const int n2l = t >> 4;
                float o3[16];
#pragma unroll
                for (int i = 0; i < 16; ++i) o3[i] = 0.f;
#pragma unroll
                for (int n3l = 0; n3l < 4; ++n3l) {
                    const int rb = T2S + (n2l * 8 + n3h * 4 + n3l) * 36;
                    float rv[32];
#pragma unroll
                    for (int g = 0; g < 8; ++g) {
                        const float4 v = *(const float4*)&smem[rb + g * 4];
                        rv[g*4+0] = v.x; rv[g*4+1] = v.y; rv[g*4+2] = v.z; rv[g*4+3] = v.w;
                    }
                    const int wb = WC2 + ((q2 * 4 + m3) * 8 + n3h * 4 + n3l) * 2;
                    const float w0 = smem[wb], w1 = smem[wb + 1];
#pragma unroll
                    for (int m45 = 0; m45 < 16; ++m45)
                        o3[m45] = fmaf(rv[m45*2], w0, fmaf(rv[m45*2+1], w1, o3[m45]));
                }
#pragma unroll
                for (int k = 0; k < 16; ++k) o3[k] += __shfl_xor(o3[k], 1);
                const int row = n2h * 16 + n2l * 4 + m3;   // = n2*4 + m3
#pragma unroll
                for (int k = 0; k < 8; ++k) {
                    const float v = n3h ? o3[8 + k] : o3[k];
                    smem[T3S + row * 34 + (n3h * 8 + k) * 2 + q2] = v;
                }
            }
        } // n2h

        // ---- step 4: contract n2,q2 -> regT4 (C1 uniform: s_load)
        {
            const int m3 = t >> 4, m4 = (t >> 2) & 3, m5 = t & 3;
            float2 zz[8];
#pragma unroll
            for (int n2 = 0; n2 < 8; ++n2)
                zz[n2] = *(const float2*)&smem[T3S + (n2 * 4 + m3) * 34 + (m4 * 4 + m5) * 2];
#pragma unroll
            for (int jj = 0; jj < 4; ++jj)
#pragma unroll
            for (int q1 = 0; q1 < 3; ++q1) {
                float sa = regT4[jj * 9 + n1 * 3 + q1];
#pragma unroll
                for (int n2g = 0; n2g < 4; ++n2g) {
                    const float4 w = *(const float4*)(g1 + ((q1 * 4 + jj) * 8 + n2g * 2) * 2);
                    sa = fmaf(zz[n2g*2].x,   w.x, sa);
                    sa = fmaf(zz[n2g*2].y,   w.y, sa);
                    sa = fmaf(zz[n2g*2+1].x, w.z, sa);
                    sa = fmaf(zz[n2g*2+1].y, w.w, sa);
                }
                regT4[jj * 9 + n1 * 3 + q1] = sa;
            }
        }
    } // n1  (no barriers anywhere in the loop)

    __syncthreads();   // phase boundary: h1 overlays T2 zones

    // ---- step 5: contract n1,q1 + bias + relu -> h1 (C0 uniform: s_load)
#pragma unroll
    for (int jj = 0; jj < 4; ++jj) {
        float bia[8];
#pragma unroll
        for (int m1 = 0; m1 < 8; ++m1) bia[m1] = b1g[m1 * 256 + jj * 64 + t];
#pragma unroll
        for (int m1 = 0; m1 < 8; ++m1) {
            float sa = bia[m1];
#pragma unroll
            for (int n1 = 0; n1 < 3; ++n1)
#pragma unroll
            for (int q1 = 0; q1 < 3; ++q1)
                sa = fmaf(regT4[jj * 9 + n1 * 3 + q1], g0[(m1 * 3 + n1) * 3 + q1], sa);
            smem[H1O + m1 * 256 + jj * 64 + t] = fmaxf(sa, 0.f);
        }
    }
    __syncthreads();

    // ================= layer 2 (right-to-left) =================
    // L2ab fused: per p3 read h1[16] from LDS, apply u4 (L2a) in registers,
    // contract n4,q4 (L2b) -> B row. A-buffer and one barrier eliminated.
#pragma unroll
    for (int pq = 0; pq < 2; ++pq) {
        const int p3 = 2 * t + pq;
        float o[8];
#pragma unroll
        for (int i = 0; i < 8; ++i) o[i] = 0.f;
#pragma unroll
        for (int n4 = 0; n4 < 4; ++n4) {
            const float4 hv = *(const float4*)&smem[H1O + (p3 * 4 + n4) * 4];
            const float ax = hv.x*u4[0]  + hv.y*u4[1]  + hv.z*u4[2]  + hv.w*u4[3];   // m5=0,q4=0
            const float ay = hv.x*u4[8]  + hv.y*u4[9]  + hv.z*u4[10] + hv.w*u4[11];  // m5=0,q4=1
            const float az = hv.x*u4[4]  + hv.y*u4[5]  + hv.z*u4[6]  + hv.w*u4[7];   // m5=1,q4=0
            const float aw = hv.x*u4[12] + hv.y*u4[13] + hv.z*u4[14] + hv.w*u4[15];  // m5=1,q4=1
#pragma unroll
            for (int q4 = 0; q4 < 2; ++q4) {
                const float a0 = q4 ? ay : ax;   // m5=0
                const float a1 = q4 ? aw : az;   // m5=1
#pragma unroll
                for (int q3 = 0; q3 < 2; ++q3)
#pragma unroll
                for (int m4 = 0; m4 < 2; ++m4) {
                    const float w = u3[((q3 * 2 + m4) * 4 + n4) * 2 + q4];
                    o[(m4 * 2 + 0) * 2 + q3] = fmaf(a0, w, o[(m4 * 2 + 0) * 2 + q3]);
                    o[(m4 * 2 + 1) * 2 + q3] = fmaf(a1, w, o[(m4 * 2 + 1) * 2 + q3]);
                }
            }
        }
#pragma unroll
        for (int k = 0; k < 8; ++k) smem[BO + p3 * 9 + k] = o[k];
    }
    __syncthreads();

    // L2c: contract n3(4),q3 -> C[p2][(m3*4+m45)*2+q2]  (U2 uniform)
    if (t < 32) {
        float o[16];
#pragma unroll
        for (int i = 0; i < 16; ++i) o[i] = 0.f;
#pragma unroll
        for (int n3 = 0; n3 < 4; ++n3)
#pragma unroll
        for (int q3 = 0; q3 < 2; ++q3) {
            float zb[4];
#pragma unroll
            for (int m45 = 0; m45 < 4; ++m45)
                zb[m45] = smem[BO + (t * 4 + n3) * 9 + m45 * 2 + q3];
#pragma unroll
            for (int m3 = 0; m3 < 2; ++m3)
#pragma unroll
            for (int q2 = 0; q2 < 2; ++q2) {
                const float w = u2[((q2 * 2 + m3) * 4 + n3) * 2 + q3];
#pragma unroll
                for (int m45 = 0; m45 < 4; ++m45)
                    o[(m3 * 4 + m45) * 2 + q2] = fmaf(zb[m45], w, o[(m3 * 4 + m45) * 2 + q2]);
            }
        }
#pragma unroll
        for (int k = 0; k < 16; ++k) smem[CO + t * 17 + k] = o[k];
    }
    __syncthreads();

    // L2d: contract n2(4),q2 -> D[s][n1*2+q1]  (U1 non-uniform: LDS)
    if (t < 32) {
        const int n1 = t >> 2, m2 = (t >> 1) & 1, m3 = t & 1;
        float o[8];
#pragma unroll
        for (int i = 0; i < 8; ++i) o[i] = 0.f;
#pragma unroll
        for (int n2 = 0; n2 < 4; ++n2)
#pragma unroll
        for (int q2 = 0; q2 < 2; ++q2) {
            float cb[4];
#pragma unroll
            for (int m45 = 0; m45 < 4; ++m45)
                cb[m45] = smem[CO + (n1 * 4 + n2) * 17 + (m3 * 4 + m45) * 2 + q2];
#pragma unroll
            for (int q1 = 0; q1 < 2; ++q1) {
                const float w = smem[WU1 + ((q1 * 2 + m2) * 4 + n2) * 2 + q2];
#pragma unroll
                for (int m45 = 0; m45 < 4; ++m45)
                    o[m45 * 2 + q1] = fmaf(cb[m45], w, o[m45 * 2 + q1]);
            }
        }
#pragma unroll
        for (int m45 = 0; m45 < 4; ++m45)
#pragma unroll
        for (int q1 = 0; q1 < 2; ++q1)
            smem[DO + (m2 * 8 + m3 * 4 + m45) * 17 + n1 * 2 + q1] = o[m45 * 2 + q1];
    }
    __syncthreads();

    // L2e: contract n1(8),q1 + bias + relu -> h2  (U0 uniform)
    if (t < 16) {
        float o[4];
#pragma unroll
        for (int i = 0; i < 4; ++i) o[i] = 0.f;
#pragma unroll
        for (int n1 = 0; n1 < 8; ++n1)
#pragma unroll
        for (int q1 = 0; q1 < 2; ++q1) {
            const float dv = smem[DO + t * 17 + n1 * 2 + q1];
#pragma unroll
            for (int m1 = 0; m1 < 4; ++m1)
                o[m1] = fmaf(dv, u0[(m1 * 8 + n1) * 2 + q1], o[m1]);
        }
#pragma unroll
        for (int m1 = 0; m1 < 4; ++m1)
            smem[H2O + m1 * 16 + t] = fmaxf(o[m1] + b2g[m1 * 16 + t], 0.f);
    }
    __syncthreads();

    // ---- layer 3 dense (W3 32x64 from d_ws) + relu ----
    if (t < 32) {
        const float4* wr = (const float4*)(w3g + t * 64);
        float sa = b3g[t];
#pragma unroll
        for (int g = 0; g < 16; ++g) {
            const float4 w4 = wr[g];
            sa = fmaf(w4.x, smem[H2O + g*4 + 0],
                 fmaf(w4.y, smem[H2O + g*4 + 1],
                 fmaf(w4.z, smem[H2O + g*4 + 2],
                 fmaf(w4.w, smem[H2O + g*4 + 3], sa))));
        }
        smem[H3O + t] = fmaxf(sa, 0.f);
    }
    __syncthreads();

    // ---- head: logits + log_softmax ----
    {
        const int k = t & 31;
        float pr = smem[H3O + k] * Wmg[t];   // t = c*32 + k
#pragma unroll
        for (int d = 16; d >= 1; d >>= 1) pr += __shfl_xor(pr, d);
        const float l0 = __shfl(pr, 0) + blg[0];
        const float l1 = __shfl(pr, 32) + blg[1];
        if (t == 0) {
            const float mm = fmaxf(l0, l1);
            const float lse = mm + logf(expf(l0 - mm) + expf(l1 - mm));
            out[(size_t)b * 2 + 0] = l0 - lse;
            out[(size_t)b * 2 + 1] = l1 - lse;
        }
    }
}

extern "C" void kernel_launch(void* const* d_in, const int* in_sizes, int n_in,
                              void* d_out, int out_size, void* d_ws, size_t ws_size,
                              hipStream_t stream) {
    const float* x    = (const float*)d_in[0];
    const float* l1c0 = (const float*)d_in[1];
    const float* l1c1 = (const float*)d_in[2];
    const float* l1c2 = (const float*)d_in[3];
    const float* l1c3 = (const float*)d_in[4];
    const float* l1c4 = (const float*)d_in[5];
    const float* b1   = (const float*)d_in[6];
    const float* l2c0 = (const float*)d_in[7];
    const float* l2c1 = (const float*)d_in[8];
    const float* l2c2 = (const float*)d_in[9];
    const float* l2c3 = (const float*)d_in[10];
    const float* l2c4 = (const float*)d_in[11];
    const float* b2   = (const float*)d_in[12];
    const float* l3c0 = (const float*)d_in[13];
    const float* l3c1 = (const float*)d_in[14];
    const float* l3c2 = (const float*)d_in[15];
    const float* l3c3 = (const float*)d_in[16];
    const float* l3c4 = (const float*)d_in[17];
    const float* b3   = (const float*)d_in[18];
    const float* Wm   = (const float*)d_in[19];
    const float* bl   = (const float*)d_in[20];
    float* W3 = (float*)d_ws;  // 2048 floats scratch

    tt_setup_w3<<<8, 256, 0, stream>>>(l3c0, l3c1, l3c2, l3c3, l3c4, W3);
    tt_main<<<2048, 64, 0, stream>>>(x, l1c0, l1c1, l1c2, l1c3, l1c4, b1,
                                     l2c0, l2c1, l2c2, l2c3, l2c4, b2, b3,
                                     Wm, bl, W3, (float*)d_out);
}

// Round 5
// 204.355 us; speedup vs baseline: 1.1786x; 1.0901x over previous
//
#include <hip/hip_runtime.h>
#include <math.h>

// ---------------- LDS layout (floats), per 64-thread (1-wave) block ----------
// R0 layout, minus the A-buffer (L2a fused into L2b in registers).
#define WC3  0      // l1c3 [q3][m4][n4][q4]            128
#define WC2  128    // l1c2 [q2][m3][n3][q3]            128
#define WU1  256    // l2c1                              32  -> 288
#define T2S  288    // [32 prefixes][36]  (pad 36: b128-aligned rows)  1152 -> 1440
#define T3S  1440   // [32 rows][34]      (pad 34: b64-aligned)        1088 -> 2528
#define H1O  288    // h1 (2048) overlays T2S/T3S after layer-1 slices  -> 2336
#define BO   2528   // B[128][9] = 1152 (after T3S; h1 stays live)      -> 3680
#define CO   1440   // C[32][17] = 544  (h1/T3 dead by L2c)
#define DO   1984   // D[16][17] = 272
#define H2O  2256   // 64
#define H3O  2320   // 32 -> 2352
#define LDS_FLOATS 3680   // 14720 B -> 10 blocks/CU cap; grid caps at 8 waves/CU

// Setup: dense layer-3 matrix W3[mi(32)][nj(64)] from TT cores (tiny).
__global__ void tt_setup_w3(const float* __restrict__ v0, const float* __restrict__ v1,
                            const float* __restrict__ v2, const float* __restrict__ v3,
                            const float* __restrict__ v4, float* __restrict__ w3) {
    int i = blockIdx.x * 256 + threadIdx.x;
    if (i >= 2048) return;
    int mi = i >> 6, nj = i & 63;
    int m1 = (mi >> 4) & 1, m2 = (mi >> 3) & 1, m3 = (mi >> 2) & 1, m4 = (mi >> 1) & 1, m5 = mi & 1;
    int n1 = (nj >> 4) & 3, n2 = (nj >> 3) & 1, n3 = (nj >> 2) & 1, n4 = (nj >> 1) & 1, n5 = nj & 1;
    float s = 0.f;
#pragma unroll
    for (int q1 = 0; q1 < 2; ++q1) {
        float a1 = v0[(m1 * 4 + n1) * 2 + q1];
#pragma unroll
        for (int q2 = 0; q2 < 2; ++q2) {
            float a2 = a1 * v1[((q1 * 2 + m2) * 2 + n2) * 2 + q2];
#pragma unroll
            for (int q3 = 0; q3 < 2; ++q3) {
                float a3 = a2 * v2[((q2 * 2 + m3) * 2 + n3) * 2 + q3];
#pragma unroll
                for (int q4 = 0; q4 < 2; ++q4)
                    s = fmaf(a3 * v3[((q3 * 2 + m4) * 2 + n4) * 2 + q4],
                             v4[(q4 * 2 + m5) * 2 + n5], s);
            }
        }
    }
    w3[i] = s;
}

__global__ __launch_bounds__(64, 2)
void tt_main(const float* __restrict__ x,
             const float* __restrict__ g0, const float* __restrict__ g1,
             const float* __restrict__ g2, const float* __restrict__ g3,
             const float* __restrict__ g4, const float* __restrict__ b1g,
             const float* __restrict__ u0, const float* __restrict__ u1,
             const float* __restrict__ u2, const float* __restrict__ u3,
             const float* __restrict__ u4, const float* __restrict__ b2g,
             const float* __restrict__ b3g,
             const float* __restrict__ Wmg, const float* __restrict__ blg,
             const float* __restrict__ w3g,
             float* __restrict__ out)
{
    __shared__ float smem[LDS_FLOATS];
    const int t = threadIdx.x;
    const int b = blockIdx.x;
    const float* xb = x + (size_t)b * 12288;

    // ---- issue x loads for subslice 0 (lane t owns 32 contiguous floats) ----
    float xv[32];
    {
        const float4* xq = (const float4*)xb + t * 8;
#pragma unroll
        for (int i = 0; i < 8; ++i) {
            const float4 v = xq[i];
            xv[i*4+0] = v.x; xv[i*4+1] = v.y; xv[i*4+2] = v.z; xv[i*4+3] = v.w;
        }
    }

    // ---- non-uniformly-indexed weights to LDS ----
    smem[WC3 + t] = g3[t];  smem[WC3 + 64 + t] = g3[64 + t];
    smem[WC2 + t] = g2[t];  smem[WC2 + 64 + t] = g2[64 + t];
    if (t < 32) smem[WU1 + t] = u1[t];
    __syncthreads();  // weights ready

    const int h = t & 1;       // n4-half owned by this lane
    const int p = t >> 1;      // subslice-local prefix (n2l*8 + n3)

    float regT4[36];           // [jj(4)][n1(3)*3+q1(3)] accumulated across slices
#pragma unroll
    for (int i = 0; i < 36; ++i) regT4[i] = 0.f;

#pragma unroll
    for (int n1 = 0; n1 < 3; ++n1) {
#pragma unroll
        for (int n2h = 0; n2h < 2; ++n2h) {
            const int s = n1 * 2 + n2h;

            // ---- step 1: t1[n4l*8 + m5*2+q4] = sum_n5 x * C4  (C4 uniform: s_load)
            float t1[32];
#pragma unroll
            for (int m5 = 0; m5 < 4; ++m5)
#pragma unroll
            for (int q4 = 0; q4 < 2; ++q4) {
                const float* w = g4 + (q4 * 4 + m5) * 8;
#pragma unroll
                for (int n4l = 0; n4l < 4; ++n4l) {
                    float sa = xv[n4l*8+0] * w[0];
#pragma unroll
                    for (int n5 = 1; n5 < 8; ++n5) sa = fmaf(xv[n4l*8+n5], w[n5], sa);
                    t1[n4l*8 + m5*2 + q4] = sa;
                }
            }

            // xv is dead: prefetch next slab INTO xv (zero extra registers;
            // latency hides under steps 2-4 + barriers of this slice).
            if (s < 5) {
                const float4* xq = (const float4*)xb + (s + 1) * 512 + t * 8;
#pragma unroll
                for (int i = 0; i < 8; ++i) {
                    const float4 v = xq[i];
                    xv[i*4+0] = v.x; xv[i*4+1] = v.y; xv[i*4+2] = v.z; xv[i*4+3] = v.w;
                }
            }

            // ---- step 2: acc[m4*4+m5] (q3 = h), contract n4 (own half, then
            //      partner's half via shfl_xor) and q4
            float acc[16];
#pragma unroll
            for (int i = 0; i < 16; ++i) acc[i] = 0.f;
#pragma unroll
            for (int pass = 0; pass < 2; ++pass) {
                const int hh = (pass == 0) ? h : (1 - h);   // n4-half of current t1
                if (pass == 1) {
#pragma unroll
                    for (int i = 0; i < 32; ++i) t1[i] = __shfl_xor(t1[i], 1);
                }
#pragma unroll
                for (int m4 = 0; m4 < 4; ++m4) {
                    const int cbase = WC3 + ((h * 4 + m4) * 8 + hh * 4) * 2;  // q3 = h
                    const float4 c0 = *(const float4*)&smem[cbase];
                    const float4 c1 = *(const float4*)&smem[cbase + 4];
                    const float cs[8] = {c0.x, c0.y, c0.z, c0.w, c1.x, c1.y, c1.z, c1.w};
#pragma unroll
                    for (int m5 = 0; m5 < 4; ++m5) {
                        float sa = acc[m4*4+m5];
#pragma unroll
                        for (int n4l = 0; n4l < 4; ++n4l)
#pragma unroll
                        for (int q4 = 0; q4 < 2; ++q4)
                            sa = fmaf(t1[n4l*8 + m5*2 + q4], cs[n4l*2 + q4], sa);
                        acc[m4*4+m5] = sa;
                    }
                }
            }

            __syncthreads();   // prior readers of T2S/T3S done
#pragma unroll
            for (int m45 = 0; m45 < 16; ++m45)
                smem[T2S + p * 36 + m45 * 2 + h] = acc[m45];
            __syncthreads();   // T2s ready

            // ---- step 3: contract n3 (half per lane) & q3 -> T3 rows
            {
                const int n3h = t & 1;
                const int q2  = (t >> 1) & 1;
                const int m3  = (t >> 2) & 3;
                const int n2l = t >> 4;
                float o3[16];
#pragma unroll
                for (int i = 0; i < 16; ++i) o3[i] = 0.f;
#pragma unroll
                for (int n3l = 0; n3l < 4; ++n3l) {
                    const int rb = T2S + (n2l * 8 + n3h * 4 + n3l) * 36;
                    float rv[32];
#pragma unroll
                    for (int g = 0; g < 8; ++g) {
                        const float4 v = *(const float4*)&smem[rb + g * 4];
                        rv[g*4+0] = v.x; rv[g*4+1] = v.y; rv[g*4+2] = v.z; rv[g*4+3] = v.w;
                    }
                    const int wb = WC2 + ((q2 * 4 + m3) * 8 + n3h * 4 + n3l) * 2;
                    const float w0 = smem[wb], w1 = smem[wb + 1];
#pragma unroll
                    for (int m45 = 0; m45 < 16; ++m45)
                        o3[m45] = fmaf(rv[m45*2], w0, fmaf(rv[m45*2+1], w1, o3[m45]));
                }
#pragma unroll
                for (int k = 0; k < 16; ++k) o3[k] += __shfl_xor(o3[k], 1);
                const int row = n2h * 16 + n2l * 4 + m3;   // = n2*4 + m3
#pragma unroll
                for (int k = 0; k < 8; ++k) {
                    const float v = n3h ? o3[8 + k] : o3[k];
                    smem[T3S + row * 34 + (n3h * 8 + k) * 2 + q2] = v;
                }
            }
        } // n2h
        __syncthreads();   // T3 complete for this n1

        // ---- step 4: contract n2,q2 -> regT4 (C1 uniform: s_load)
        {
            const int m3 = t >> 4, m4 = (t >> 2) & 3, m5 = t & 3;
            float2 zz[8];
#pragma unroll
            for (int n2 = 0; n2 < 8; ++n2)
                zz[n2] = *(const float2*)&smem[T3S + (n2 * 4 + m3) * 34 + (m4 * 4 + m5) * 2];
#pragma unroll
            for (int jj = 0; jj < 4; ++jj)
#pragma unroll
            for (int q1 = 0; q1 < 3; ++q1) {
                float sa = regT4[jj * 9 + n1 * 3 + q1];
#pragma unroll
                for (int n2g = 0; n2g < 4; ++n2g) {
                    const float4 w = *(const float4*)(g1 + ((q1 * 4 + jj) * 8 + n2g * 2) * 2);
                    sa = fmaf(zz[n2g*2].x,   w.x, sa);
                    sa = fmaf(zz[n2g*2].y,   w.y, sa);
                    sa = fmaf(zz[n2g*2+1].x, w.z, sa);
                    sa = fmaf(zz[n2g*2+1].y, w.w, sa);
                }
                regT4[jj * 9 + n1 * 3 + q1] = sa;
            }
        }
    } // n1
    __syncthreads();   // T3 reads done; h1 may overwrite T2S/T3S zone

    // ---- step 5: contract n1,q1 + bias + relu -> h1 (C0 uniform: s_load)
#pragma unroll
    for (int jj = 0; jj < 4; ++jj) {
        float bia[8];
#pragma unroll
        for (int m1 = 0; m1 < 8; ++m1) bia[m1] = b1g[m1 * 256 + jj * 64 + t];
#pragma unroll
        for (int m1 = 0; m1 < 8; ++m1) {
            float sa = bia[m1];
#pragma unroll
            for (int n1 = 0; n1 < 3; ++n1)
#pragma unroll
            for (int q1 = 0; q1 < 3; ++q1)
                sa = fmaf(regT4[jj * 9 + n1 * 3 + q1], g0[(m1 * 3 + n1) * 3 + q1], sa);
            smem[H1O + m1 * 256 + jj * 64 + t] = fmaxf(sa, 0.f);
        }
    }
    __syncthreads();

    // ================= layer 2 (right-to-left) =================
    // L2ab fused: per p3 read h1[16] from LDS, apply u4 (L2a) in registers,
    // contract n4,q4 (L2b) -> B row. A-buffer and one barrier eliminated.
#pragma unroll
    for (int pq = 0; pq < 2; ++pq) {
        const int p3 = 2 * t + pq;
        float o[8];
#pragma unroll
        for (int i = 0; i < 8; ++i) o[i] = 0.f;
#pragma unroll
        for (int n4 = 0; n4 < 4; ++n4) {
            const float4 hv = *(const float4*)&smem[H1O + (p3 * 4 + n4) * 4];
            const float ax = hv.x*u4[0]  + hv.y*u4[1]  + hv.z*u4[2]  + hv.w*u4[3];   // m5=0,q4=0
            const float ay = hv.x*u4[8]  + hv.y*u4[9]  + hv.z*u4[10] + hv.w*u4[11];  // m5=0,q4=1
            const float az = hv.x*u4[4]  + hv.y*u4[5]  + hv.z*u4[6]  + hv.w*u4[7];   // m5=1,q4=0
            const float aw = hv.x*u4[12] + hv.y*u4[13] + hv.z*u4[14] + hv.w*u4[15];  // m5=1,q4=1
#pragma unroll
            for (int q4 = 0; q4 < 2; ++q4) {
                const float a0 = q4 ? ay : ax;   // m5=0
                const float a1 = q4 ? aw : az;   // m5=1
#pragma unroll
                for (int q3 = 0; q3 < 2; ++q3)
#pragma unroll
                for (int m4 = 0; m4 < 2; ++m4) {
                    const float w = u3[((q3 * 2 + m4) * 4 + n4) * 2 + q4];
                    o[(m4 * 2 + 0) * 2 + q3] = fmaf(a0, w, o[(m4 * 2 + 0) * 2 + q3]);
                    o[(m4 * 2 + 1) * 2 + q3] = fmaf(a1, w, o[(m4 * 2 + 1) * 2 + q3]);
                }
            }
        }
#pragma unroll
        for (int k = 0; k < 8; ++k) smem[BO + p3 * 9 + k] = o[k];
    }
    __syncthreads();

    // L2c: contract n3(4),q3 -> C[p2][(m3*4+m45)*2+q2]  (U2 uniform)
    if (t < 32) {
        float o[16];
#pragma unroll
        for (int i = 0; i < 16; ++i) o[i] = 0.f;
#pragma unroll
        for (int n3 = 0; n3 < 4; ++n3)
#pragma unroll
        for (int q3 = 0; q3 < 2; ++q3) {
            float zb[4];
#pragma unroll
            for (int m45 = 0; m45 < 4; ++m45)
                zb[m45] = smem[BO + (t * 4 + n3) * 9 + m45 * 2 + q3];
#pragma unroll
            for (int m3 = 0; m3 < 2; ++m3)
#pragma unroll
            for (int q2 = 0; q2 < 2; ++q2) {
                const float w = u2[((q2 * 2 + m3) * 4 + n3) * 2 + q3];
#pragma unroll
                for (int m45 = 0; m45 < 4; ++m45)
                    o[(m3 * 4 + m45) * 2 + q2] = fmaf(zb[m45], w, o[(m3 * 4 + m45) * 2 + q2]);
            }
        }
#pragma unroll
        for (int k = 0; k < 16; ++k) smem[CO + t * 17 + k] = o[k];
    }
    __syncthreads();

    // L2d: contract n2(4),q2 -> D[s][n1*2+q1]  (U1 non-uniform: LDS)
    if (t < 32) {
        const int n1 = t >> 2, m2 = (t >> 1) & 1, m3 = t & 1;
        float o[8];
#pragma unroll
        for (int i = 0; i < 8; ++i) o[i] = 0.f;
#pragma unroll
        for (int n2 = 0; n2 < 4; ++n2)
#pragma unroll
        for (int q2 = 0; q2 < 2; ++q2) {
            float cb[4];
#pragma unroll
            for (int m45 = 0; m45 < 4; ++m45)
                cb[m45] = smem[CO + (n1 * 4 + n2) * 17 + (m3 * 4 + m45) * 2 + q2];
#pragma unroll
            for (int q1 = 0; q1 < 2; ++q1) {
                const float w = smem[WU1 + ((q1 * 2 + m2) * 4 + n2) * 2 + q2];
#pragma unroll
                for (int m45 = 0; m45 < 4; ++m45)
                    o[m45 * 2 + q1] = fmaf(cb[m45], w, o[m45 * 2 + q1]);
            }
        }
#pragma unroll
        for (int m45 = 0; m45 < 4; ++m45)
#pragma unroll
        for (int q1 = 0; q1 < 2; ++q1)
            smem[DO + (m2 * 8 + m3 * 4 + m45) * 17 + n1 * 2 + q1] = o[m45 * 2 + q1];
    }
    __syncthreads();

    // L2e: contract n1(8),q1 + bias + relu -> h2  (U0 uniform)
    if (t < 16) {
        float o[4];
#pragma unroll
        for (int i = 0; i < 4; ++i) o[i] = 0.f;
#pragma unroll
        for (int n1 = 0; n1 < 8; ++n1)
#pragma unroll
        for (int q1 = 0; q1 < 2; ++q1) {
            const float dv = smem[DO + t * 17 + n1 * 2 + q1];
#pragma unroll
            for (int m1 = 0; m1 < 4; ++m1)
                o[m1] = fmaf(dv, u0[(m1 * 8 + n1) * 2 + q1], o[m1]);
        }
#pragma unroll
        for (int m1 = 0; m1 < 4; ++m1)
            smem[H2O + m1 * 16 + t] = fmaxf(o[m1] + b2g[m1 * 16 + t], 0.f);
    }
    __syncthreads();

    // ---- layer 3 dense (W3 32x64 from d_ws) + relu ----
    if (t < 32) {
        const float4* wr = (const float4*)(w3g + t * 64);
        float sa = b3g[t];
#pragma unroll
        for (int g = 0; g < 16; ++g) {
            const float4 w4 = wr[g];
            sa = fmaf(w4.x, smem[H2O + g*4 + 0],
                 fmaf(w4.y, smem[H2O + g*4 + 1],
                 fmaf(w4.z, smem[H2O + g*4 + 2],
                 fmaf(w4.w, smem[H2O + g*4 + 3], sa))));
        }
        smem[H3O + t] = fmaxf(sa, 0.f);
    }
    __syncthreads();

    // ---- head: logits + log_softmax ----
    {
        const int k = t & 31;
        float pr = smem[H3O + k] * Wmg[t];   // t = c*32 + k
#pragma unroll
        for (int d = 16; d >= 1; d >>= 1) pr += __shfl_xor(pr, d);
        const float l0 = __shfl(pr, 0) + blg[0];
        const float l1 = __shfl(pr, 32) + blg[1];
        if (t == 0) {
            const float mm = fmaxf(l0, l1);
            const float lse = mm + logf(expf(l0 - mm) + expf(l1 - mm));
            out[(size_t)b * 2 + 0] = l0 - lse;
            out[(size_t)b * 2 + 1] = l1 - lse;
        }
    }
}

extern "C" void kernel_launch(void* const* d_in, const int* in_sizes, int n_in,
                              void* d_out, int out_size, void* d_ws, size_t ws_size,
                              hipStream_t stream) {
    const float* x    = (const float*)d_in[0];
    const float* l1c0 = (const float*)d_in[1];
    const float* l1c1 = (const float*)d_in[2];
    const float* l1c2 = (const float*)d_in[3];
    const float* l1c3 = (const float*)d_in[4];
    const float* l1c4 = (const float*)d_in[5];
    const float* b1   = (const float*)d_in[6];
    const float* l2c0 = (const float*)d_in[7];
    const float* l2c1 = (const float*)d_in[8];
    const float* l2c2 = (const float*)d_in[9];
    const float* l2c3 = (const float*)d_in[10];
    const float* l2c4 = (const float*)d_in[11];
    const float* b2   = (const float*)d_in[12];
    const float* l3c0 = (const float*)d_in[13];
    const float* l3c1 = (const float*)d_in[14];
    const float* l3c2 = (const float*)d_in[15];
    const float* l3c3 = (const float*)d_in[16];
    const float* l3c4 = (const float*)d_in[17];
    const float* b3   = (const float*)d_in[18];
    const float* Wm   = (const float*)d_in[19];
    const float* bl   = (const float*)d_in[20];
    float* W3 = (float*)d_ws;  // 2048 floats scratch

    tt_setup_w3<<<8, 256, 0, stream>>>(l3c0, l3c1, l3c2, l3c3, l3c4, W3);
    tt_main<<<2048, 64, 0, stream>>>(x, l1c0, l1c1, l1c2, l1c3, l1c4, b1,
                                     l2c0, l2c1, l2c2, l2c3, l2c4, b2, b3,
                                     Wm, bl, W3, (float*)d_out);
}